// Round 3
// baseline (605.081 us; speedup 1.0000x reference)
//
#include <hip/hip_runtime.h>

// SCAM fused kernel v2 for MI355X (gfx950).
// One block per (b,h) slice (grid 1024 = 256 CU x 4 resident blocks).
// Key changes vs v1: just-in-time fragment builds straight from global (no
// load_side LDS round trip, no long-lived fragment arrays -> no spills),
// weights read as direct global B-fragments (no stage_w), PV fused with
// epilogue. LDS = 32 KB slot + 2 KB colred -> 4 blocks/CU.

typedef __attribute__((ext_vector_type(8))) __bf16 bf16x8;
typedef __attribute__((ext_vector_type(4))) __bf16 bf16x4;
typedef __attribute__((ext_vector_type(4))) float f4;

#define MFMA(A, B, C) __builtin_amdgcn_mfma_f32_16x16x32_bf16((A), (B), (C), 0, 0, 0)
#define SCALE_QK 0.08838834764831845f  // 128^-0.5

// XOR-swizzled LDS offset for a [128][128] bf16 slot (256 B row stride).
static __device__ __forceinline__ int eoff(int n, int k) {
  return (n << 8) + ((((k >> 3) ^ (n & 7)) << 4) | ((k & 7) << 1));
}

// Prep: transpose 4 fp32 [k][n] weight matrices to bf16 [n][k] in workspace.
__global__ void prep_w(const float* __restrict__ w0, const float* __restrict__ w1,
                       const float* __restrict__ w2, const float* __restrict__ w3,
                       __bf16* __restrict__ out) {
  int m = blockIdx.y;
  const float* src = (m == 0) ? w0 : (m == 1) ? w1 : (m == 2) ? w2 : w3;
  int t = blockIdx.x * 256 + threadIdx.x;  // 0..16383
  int k = t >> 7, n = t & 127;
  out[m * 16384 + n * 128 + k] = (__bf16)src[k * 128 + n];
}

// Raw-x A-fragments direct from global (fp32 -> bf16 cvt), no LDS.
static __device__ __forceinline__ void build_x_frags(const float* __restrict__ xp,
                                                     size_t base, int w, int l16,
                                                     int quad, bf16x8* F) {
#pragma unroll
  for (int mt = 0; mt < 2; ++mt) {
    const float* rp = xp + base + (size_t)(w * 32 + mt * 16 + l16) * 128;
#pragma unroll
    for (int ks = 0; ks < 4; ++ks) {
      int k0 = ks * 32 + quad * 8;
      float4 p0 = *(const float4*)(rp + k0);
      float4 p1 = *(const float4*)(rp + k0 + 4);
      bf16x8 f;
      f[0] = (__bf16)p0.x; f[1] = (__bf16)p0.y; f[2] = (__bf16)p0.z; f[3] = (__bf16)p0.w;
      f[4] = (__bf16)p1.x; f[5] = (__bf16)p1.y; f[6] = (__bf16)p1.z; f[7] = (__bf16)p1.w;
      F[mt * 4 + ks] = f;
    }
  }
}

// LayerNorm A-fragments: load x in fragment pattern, stats via in-lane sums +
// cross-quad shuffles (row = 4 quads x 32 elems), then normalize + affine.
static __device__ __forceinline__ void build_ln_frags(const float* __restrict__ xp,
                                                      size_t base,
                                                      const float* __restrict__ g,
                                                      const float* __restrict__ b,
                                                      int w, int l16, int quad,
                                                      bf16x8* F) {
#pragma unroll
  for (int mt = 0; mt < 2; ++mt) {
    const float* rp = xp + base + (size_t)(w * 32 + mt * 16 + l16) * 128;
    float4 v[8];
#pragma unroll
    for (int ks = 0; ks < 4; ++ks) {
      int k0 = ks * 32 + quad * 8;
      v[ks * 2] = *(const float4*)(rp + k0);
      v[ks * 2 + 1] = *(const float4*)(rp + k0 + 4);
    }
    float s = 0.f, s2 = 0.f;
#pragma unroll
    for (int t = 0; t < 8; ++t) {
      s += v[t].x + v[t].y + v[t].z + v[t].w;
      s2 += v[t].x * v[t].x + v[t].y * v[t].y + v[t].z * v[t].z + v[t].w * v[t].w;
    }
    s += __shfl_xor(s, 16); s2 += __shfl_xor(s2, 16);
    s += __shfl_xor(s, 32); s2 += __shfl_xor(s2, 32);
    float mean = s * 0.0078125f;
    float var = s2 * 0.0078125f - mean * mean;
    float rstd = rsqrtf(var + 1e-6f);
#pragma unroll
    for (int ks = 0; ks < 4; ++ks) {
      int k0 = ks * 32 + quad * 8;
      float4 g0 = *(const float4*)(g + k0), g1 = *(const float4*)(g + k0 + 4);
      float4 b0 = *(const float4*)(b + k0), b1 = *(const float4*)(b + k0 + 4);
      float4 p0 = v[ks * 2], p1 = v[ks * 2 + 1];
      bf16x8 f;
      f[0] = (__bf16)((p0.x - mean) * rstd * g0.x + b0.x);
      f[1] = (__bf16)((p0.y - mean) * rstd * g0.y + b0.y);
      f[2] = (__bf16)((p0.z - mean) * rstd * g0.z + b0.z);
      f[3] = (__bf16)((p0.w - mean) * rstd * g0.w + b0.w);
      f[4] = (__bf16)((p1.x - mean) * rstd * g1.x + b1.x);
      f[5] = (__bf16)((p1.y - mean) * rstd * g1.y + b1.y);
      f[6] = (__bf16)((p1.z - mean) * rstd * g1.z + b1.z);
      f[7] = (__bf16)((p1.w - mean) * rstd * g1.w + b1.w);
      F[mt * 4 + ks] = f;
    }
  }
}

// out = A @ W + bias (W B-frags direct from global), C row-major -> slot.
static __device__ __forceinline__ void proj_q(const bf16x8* aF,
                                              const __bf16* __restrict__ wTm, char* slot,
                                              const float* __restrict__ bias, float scale,
                                              int w, int l16, int quad) {
#pragma unroll
  for (int nt = 0; nt < 8; ++nt) {
    int n = nt * 16 + l16;
    f4 a0 = {0.f, 0.f, 0.f, 0.f}, a1 = {0.f, 0.f, 0.f, 0.f};
#pragma unroll
    for (int ks = 0; ks < 4; ++ks) {
      bf16x8 bf = *(const bf16x8*)(wTm + n * 128 + ks * 32 + quad * 8);
      a0 = MFMA(aF[ks], bf, a0);
      a1 = MFMA(aF[4 + ks], bf, a1);
    }
    float bs = bias[n];
#pragma unroll
    for (int mt = 0; mt < 2; ++mt) {
      f4 a = mt ? a1 : a0;
#pragma unroll
      for (int r = 0; r < 4; ++r) {
        int i = w * 32 + mt * 16 + quad * 4 + r;
        *(__bf16*)(slot + eoff(i, n)) = (__bf16)((a[r] + bs) * scale);
      }
    }
  }
}

// out = A @ W + bias, C TRANSPOSED -> slot [c][j] (B-operand layout for PV).
static __device__ __forceinline__ void proj_vT(const bf16x8* aF,
                                               const __bf16* __restrict__ wTm, char* slot,
                                               const float* __restrict__ bias, int w,
                                               int l16, int quad) {
#pragma unroll
  for (int nt = 0; nt < 8; ++nt) {
    int n = nt * 16 + l16;
    f4 a0 = {0.f, 0.f, 0.f, 0.f}, a1 = {0.f, 0.f, 0.f, 0.f};
#pragma unroll
    for (int ks = 0; ks < 4; ++ks) {
      bf16x8 bf = *(const bf16x8*)(wTm + n * 128 + ks * 32 + quad * 8);
      a0 = MFMA(aF[ks], bf, a0);
      a1 = MFMA(aF[4 + ks], bf, a1);
    }
    float bs = bias[n];
#pragma unroll
    for (int mt = 0; mt < 2; ++mt) {
      f4 a = mt ? a1 : a0;
      bf16x4 vv;
#pragma unroll
      for (int r = 0; r < 4; ++r) vv[r] = (__bf16)(a[r] + bs);
      *(bf16x4*)(slot + eoff(n, w * 32 + mt * 16 + quad * 4)) = vv;
    }
  }
}

// f = P @ V (V^T in slot) fused with epilogue: out = x + scl[c] * f, fp32.
static __device__ __forceinline__ void pv_epi(const bf16x8* pF, const char* slot,
                                              const float* __restrict__ xp, size_t base,
                                              const float* __restrict__ scl,
                                              float* __restrict__ outp, int w, int l16,
                                              int quad) {
#pragma unroll
  for (int nt = 0; nt < 8; ++nt) {
    int c = nt * 16 + l16;
    f4 a0 = {0.f, 0.f, 0.f, 0.f}, a1 = {0.f, 0.f, 0.f, 0.f};
#pragma unroll
    for (int ks = 0; ks < 4; ++ks) {
      bf16x8 bf = *(const bf16x8*)(slot + eoff(c, ks * 32 + quad * 8));
      a0 = MFMA(pF[ks], bf, a0);
      a1 = MFMA(pF[4 + ks], bf, a1);
    }
    float sc = scl[c];
#pragma unroll
    for (int mt = 0; mt < 2; ++mt) {
      f4 a = mt ? a1 : a0;
#pragma unroll
      for (int r = 0; r < 4; ++r) {
        size_t off = base + (size_t)(w * 32 + mt * 16 + quad * 4 + r) * 128 + c;
        outp[off] = xp[off] + sc * a[r];
      }
    }
  }
}

static __device__ __forceinline__ void read_afrags(const char* slot, int w, int l16,
                                                   int quad, bf16x8* F) {
#pragma unroll
  for (int mt = 0; mt < 2; ++mt)
#pragma unroll
    for (int ks = 0; ks < 4; ++ks)
      F[mt * 4 + ks] =
          *(const bf16x8*)(slot + eoff(w * 32 + mt * 16 + l16, ks * 32 + quad * 8));
}

__global__ __launch_bounds__(256, 4) void scam_fused(
    const float* __restrict__ xl, const float* __restrict__ xr,
    const float* __restrict__ gl, const float* __restrict__ bl,
    const float* __restrict__ gr, const float* __restrict__ br,
    const __bf16* __restrict__ wT,  // 4 x [n][k] bf16: ql, qr, vl, vr
    const float* __restrict__ bql, const float* __restrict__ bqr,
    const float* __restrict__ bvl, const float* __restrict__ bvr,
    const float* __restrict__ beta, const float* __restrict__ gamma,
    float* __restrict__ out0, float* __restrict__ out1) {
  __shared__ char slot[32768];
  __shared__ float colred[512];
  int tid = threadIdx.x;
  int lane = tid & 63, w = tid >> 6;
  int quad = lane >> 4, l16 = lane & 15;
  size_t base = (size_t)blockIdx.x << 14;

  // ---- q_l = (ln(x_l) @ Wql + b) * SCALE -> slot -> A-frags ----
  {
    bf16x8 lF[8];
    build_ln_frags(xl, base, gl, bl, w, l16, quad, lF);
    proj_q(lF, wT, slot, bql, SCALE_QK, w, l16, quad);
  }
  __syncthreads();  // (1) q_l written
  bf16x8 qlF[8];
  read_afrags(slot, w, l16, quad, qlF);
  __syncthreads();  // (2) slot reusable

  // ---- q_r = ln(x_r) @ Wqr + b -> slot (row-major [j][c]) ----
  {
    bf16x8 lF[8];
    build_ln_frags(xr, base, gr, br, w, l16, quad, lF);
    proj_q(lF, wT + 16384, slot, bqr, 1.0f, w, l16, quad);
  }
  __syncthreads();  // (3) q_r written

  // ---- S = q_l @ q_r^T ----
  f4 sacc[2][8];
  const f4 fzero = {0.f, 0.f, 0.f, 0.f};
#pragma unroll
  for (int mt = 0; mt < 2; ++mt)
#pragma unroll
    for (int nt = 0; nt < 8; ++nt) sacc[mt][nt] = fzero;
#pragma unroll
  for (int nt = 0; nt < 8; ++nt)
#pragma unroll
    for (int ks = 0; ks < 4; ++ks) {
      bf16x8 bf = *(const bf16x8*)(slot + eoff(nt * 16 + l16, ks * 32 + quad * 8));
      sacc[0][nt] = MFMA(qlF[ks], bf, sacc[0][nt]);
      sacc[1][nt] = MFMA(qlF[4 + ks], bf, sacc[1][nt]);
    }

  // ---- dual softmax stats ----
  float rm[2][4], rinv[2][4];
#pragma unroll
  for (int mt = 0; mt < 2; ++mt)
#pragma unroll
    for (int r = 0; r < 4; ++r) {
      float m = -1e30f;
#pragma unroll
      for (int nt = 0; nt < 8; ++nt) m = fmaxf(m, sacc[mt][nt][r]);
#pragma unroll
      for (int d = 1; d < 16; d <<= 1) m = fmaxf(m, __shfl_xor(m, d));
      float s = 0.f;
#pragma unroll
      for (int nt = 0; nt < 8; ++nt) s += __expf(sacc[mt][nt][r] - m);
#pragma unroll
      for (int d = 1; d < 16; d <<= 1) s += __shfl_xor(s, d);
      rm[mt][r] = m;
      rinv[mt][r] = 1.f / s;
    }
  float cm[8], cinv[8];
#pragma unroll
  for (int nt = 0; nt < 8; ++nt) {
    float m = -1e30f;
#pragma unroll
    for (int mt = 0; mt < 2; ++mt)
#pragma unroll
      for (int r = 0; r < 4; ++r) m = fmaxf(m, sacc[mt][nt][r]);
    m = fmaxf(m, __shfl_xor(m, 16));
    m = fmaxf(m, __shfl_xor(m, 32));
    cm[nt] = m;
  }
  __syncthreads();  // (4) all waves done reading slot (S) — slot free below
  if (quad == 0) {
#pragma unroll
    for (int nt = 0; nt < 8; ++nt) colred[w * 128 + nt * 16 + l16] = cm[nt];
  }
  __syncthreads();  // (5)
#pragma unroll
  for (int nt = 0; nt < 8; ++nt) {
    float m = cm[nt];
#pragma unroll
    for (int ww = 0; ww < 4; ++ww) m = fmaxf(m, colred[ww * 128 + nt * 16 + l16]);
    cm[nt] = m;
  }
  // P_r -> slot (safe since (4)); col sums with final cm meanwhile.
#pragma unroll
  for (int mt = 0; mt < 2; ++mt)
#pragma unroll
    for (int nt = 0; nt < 8; ++nt)
#pragma unroll
      for (int r = 0; r < 4; ++r) {
        int i = w * 32 + mt * 16 + quad * 4 + r;
        *(__bf16*)(slot + eoff(i, nt * 16 + l16)) =
            (__bf16)(__expf(sacc[mt][nt][r] - rm[mt][r]) * rinv[mt][r]);
      }
#pragma unroll
  for (int nt = 0; nt < 8; ++nt) {
    float s = 0.f;
#pragma unroll
    for (int mt = 0; mt < 2; ++mt)
#pragma unroll
      for (int r = 0; r < 4; ++r) s += __expf(sacc[mt][nt][r] - cm[nt]);
    s += __shfl_xor(s, 16);
    s += __shfl_xor(s, 32);
    cinv[nt] = s;
  }
  __syncthreads();  // (6) maxes all read; P_r fully written
  if (quad == 0) {
#pragma unroll
    for (int nt = 0; nt < 8; ++nt) colred[w * 128 + nt * 16 + l16] = cinv[nt];
  }
  __syncthreads();  // (7)
#pragma unroll
  for (int nt = 0; nt < 8; ++nt) {
    float s = 0.f;
#pragma unroll
    for (int ww = 0; ww < 4; ++ww) s += colred[ww * 128 + nt * 16 + l16];
    cinv[nt] = 1.f / s;
  }
  bf16x8 prF[8];
  read_afrags(slot, w, l16, quad, prF);  // P_r complete since (6)
  __syncthreads();  // (8) slot reusable
  // P_c^T -> slot [j-row][i-col] transposed write.
#pragma unroll
  for (int mt = 0; mt < 2; ++mt)
#pragma unroll
    for (int nt = 0; nt < 8; ++nt) {
      bf16x4 pc;
#pragma unroll
      for (int r = 0; r < 4; ++r)
        pc[r] = (__bf16)(__expf(sacc[mt][nt][r] - cm[nt]) * cinv[nt]);
      *(bf16x4*)(slot + eoff(nt * 16 + l16, w * 32 + mt * 16 + quad * 4)) = pc;
    }
  __syncthreads();  // (9)
  bf16x8 pcF[8];
  read_afrags(slot, w, l16, quad, pcF);
  __syncthreads();  // (10) slot reusable

  // ---- side 0: v_r^T -> slot, f_r2l fused epilogue -> out0 ----
  {
    bf16x8 xF[8];
    build_x_frags(xr, base, w, l16, quad, xF);
    proj_vT(xF, wT + 3 * 16384, slot, bvr, w, l16, quad);
  }
  __syncthreads();  // (11)
  pv_epi(prF, slot, xl, base, beta, out0, w, l16, quad);
  __syncthreads();  // (12)

  // ---- side 1: v_l^T -> slot, f_l2r fused epilogue -> out1 ----
  {
    bf16x8 xF[8];
    build_x_frags(xl, base, w, l16, quad, xF);
    proj_vT(xF, wT + 2 * 16384, slot, bvl, w, l16, quad);
  }
  __syncthreads();  // (13)
  pv_epi(pcF, slot, xr, base, gamma, out1, w, l16, quad);
}

extern "C" void kernel_launch(void* const* d_in, const int* in_sizes, int n_in,
                              void* d_out, int out_size, void* d_ws, size_t ws_size,
                              hipStream_t stream) {
  const float* xl = (const float*)d_in[0];
  const float* xr = (const float*)d_in[1];
  const float* gl = (const float*)d_in[2];
  const float* bl = (const float*)d_in[3];
  const float* gr = (const float*)d_in[4];
  const float* br = (const float*)d_in[5];
  const float* wql = (const float*)d_in[6];
  const float* bql = (const float*)d_in[7];
  const float* wqr = (const float*)d_in[8];
  const float* bqr = (const float*)d_in[9];
  const float* wvl = (const float*)d_in[10];
  const float* bvl = (const float*)d_in[11];
  const float* wvr = (const float*)d_in[12];
  const float* bvr = (const float*)d_in[13];
  const float* beta = (const float*)d_in[14];
  const float* gamma = (const float*)d_in[15];

  __bf16* wT = (__bf16*)d_ws;   // 4 * 16384 bf16 = 128 KB scratch
  float* out0 = (float*)d_out;  // [8,128,128,128] fp32
  float* out1 = out0 + (size_t)8 * 128 * 128 * 128;

  prep_w<<<dim3(64, 4), 256, 0, stream>>>(wql, wqr, wvl, wvr, wT);
  scam_fused<<<1024, 256, 0, stream>>>(xl, xr, gl, bl, gr, br, wT, bql, bqr, bvl, bvr,
                                       beta, gamma, out0, out1);
}